// Round 5
// baseline (389.022 us; speedup 1.0000x reference)
//
#include <hip/hip_runtime.h>

typedef __attribute__((ext_vector_type(8))) __bf16 bf16x8;
typedef __attribute__((ext_vector_type(4))) short short4v;   // 4 bf16 as shorts (x16 frag)
typedef __attribute__((ext_vector_type(4))) float f32x4;
typedef __attribute__((ext_vector_type(4))) unsigned int u32x4;
typedef __attribute__((ext_vector_type(2))) unsigned int u32x2;

__device__ __forceinline__ unsigned short f2bf(float f){
    unsigned int x = __builtin_bit_cast(unsigned int, f);
    x += 0x7FFFu + ((x >> 16) & 1u);
    return (unsigned short)(x >> 16);
}
__device__ __forceinline__ unsigned int pk2(float a, float b){
    return (unsigned int)f2bf(a) | ((unsigned int)f2bf(b) << 16);
}
__device__ __forceinline__ bf16x8 ldfrag(const unsigned short* p){
    u32x4 v = *reinterpret_cast<const u32x4*>(p);
    return __builtin_bit_cast(bf16x8, v);
}
__device__ __forceinline__ bf16x8 ldf32(const float* p){
    f32x4 a = *reinterpret_cast<const f32x4*>(p);
    f32x4 b = *reinterpret_cast<const f32x4*>(p + 4);
    u32x4 r;
    r[0] = pk2(a[0], a[1]); r[1] = pk2(a[2], a[3]);
    r[2] = pk2(b[0], b[1]); r[3] = pk2(b[2], b[3]);
    return __builtin_bit_cast(bf16x8, r);
}
__device__ __forceinline__ f32x4 mfma_bf16(bf16x8 a, bf16x8 b, f32x4 c){
    return __builtin_amdgcn_mfma_f32_16x16x32_bf16(a, b, c, 0, 0, 0);
}

#if defined(__has_builtin)
#if __has_builtin(__builtin_amdgcn_mfma_f32_16x16x16bf16_1k)
#define HAVE_MFMA16 1
#endif
#endif
__device__ __forceinline__ f32x4 mfma16(short4v a, short4v b, f32x4 c){
#ifdef HAVE_MFMA16
    return __builtin_amdgcn_mfma_f32_16x16x16bf16_1k(a, b, c, 0, 0, 0);
#else
    f32x4 d;
    asm volatile("s_nop 1\n\tv_mfma_f32_16x16x16_bf16 %0, %1, %2, %3\n\ts_nop 7\n\ts_nop 7"
                 : "=v"(d) : "v"(a), "v"(b), "v"(c));
    return d;
#endif
}

#define VSTR 72

// ---------------- Kernel 0: one-time weight prep ----------------
// w1k/w1v: x32 B-frags [n*3+ks][lane][8]  (K,V projections; col e' = n*16+l15)
// w1q:     x16 A-frags (Q^T, scale folded), paired: [(qt*3+(ks>>1))][lane][8] lo=ks even hi=odd
// w2p:     x16 B-frags (proj), paired:              [(n*3+(ct>>1))][lane][8]
// bias3:   b1k[96] | b1v[96] | b1q[96] (scaled)
__global__ __launch_bounds__(256) void k_prep(const float* __restrict__ w1,
                                              const float* __restrict__ b1,
                                              const float* __restrict__ w2,
                                              unsigned short* __restrict__ w1k,
                                              unsigned short* __restrict__ w1v,
                                              unsigned short* __restrict__ w1q,
                                              unsigned short* __restrict__ w2p,
                                              float* __restrict__ bias3)
{
    const float SCALE = 0.17677669529663687f;   // 1/sqrt(32)
    int i = blockIdx.x * 256 + threadIdx.x;
    if (i < 2304){
        int half = i / 1152;                 // 0 = K (c=1), 1 = V (c=2)
        int j = i - half * 1152;
        int f = j >> 6, lane = j & 63;
        int n = f / 3, ks = f - n * 3;
        int l15 = lane & 15, qd = lane >> 4;
        int row = 3 * (n * 16 + l15) + 1 + half;
        const float* src = w1 + (size_t)row * 96 + ks * 32 + qd * 8;
        f32x4 v0 = *reinterpret_cast<const f32x4*>(src);
        f32x4 v1 = *reinterpret_cast<const f32x4*>(src + 4);
        u32x4 p;
        p[0] = pk2(v0[0], v0[1]); p[1] = pk2(v0[2], v0[3]);
        p[2] = pk2(v1[0], v1[1]); p[3] = pk2(v1[2], v1[3]);
        unsigned short* dst = (half ? w1v : w1k) + (size_t)f * 512 + lane * 8;
        *reinterpret_cast<u32x4*>(dst) = p;
    } else if (i < 4608){
        int j = i - 2304;
        int f = j >> 6, lane = j & 63;
        int qt = f / 6, ks = f - qt * 6;
        int l15 = lane & 15, qd = lane >> 4;
        int row = 3 * (qt * 16 + l15);       // c=0 (Q)
        const float* src = w1 + (size_t)row * 96 + ks * 16 + qd * 4;
        f32x4 v = *reinterpret_cast<const f32x4*>(src);
        u32x2 p;
        p[0] = pk2(v[0] * SCALE, v[1] * SCALE);
        p[1] = pk2(v[2] * SCALE, v[3] * SCALE);
        *reinterpret_cast<u32x2*>(w1q + (size_t)(qt * 3 + (ks >> 1)) * 512 + lane * 8 + (ks & 1) * 4) = p;
    } else if (i < 6912){
        int j = i - 4608;
        int f = j >> 6, lane = j & 63;
        int n = f / 6, ct = f - n * 6;
        int l15 = lane & 15, qd = lane >> 4;
        const float* src = w2 + (size_t)(n * 16 + l15) * 96 + ct * 16 + qd * 4;
        f32x4 v = *reinterpret_cast<const f32x4*>(src);
        u32x2 p;
        p[0] = pk2(v[0], v[1]); p[1] = pk2(v[2], v[3]);
        *reinterpret_cast<u32x2*>(w2p + (size_t)(n * 3 + (ct >> 1)) * 512 + lane * 8 + (ct & 1) * 4) = p;
    } else if (i < 7200){
        int e = i - 6912;
        int g = e / 96, r = e - g * 96;
        if (g == 0)      bias3[r]       = b1[3 * r + 1];
        else if (g == 1) bias3[96 + r]  = b1[3 * r + 2];
        else             bias3[192 + r] = b1[3 * r] * SCALE;
    }
}

// ---------------- Kernel 1: fused QKV + attention + projection (x16 dataflow) --------
// LDS (shorts): K [3][64][32] swizzled @0 | Vt [3][32][72] @6144 -> 26112 B total.
// Q never touches LDS (accQ -> bQ frags in regs); P never touches LDS (S^T -> bP);
// O never touches LDS (accO -> aO frags). o2 (fp32 [64][100]) aliases K+Vt for scatter.
// Unit map: wave w owns q-rows w*16..w*16+15 for ALL 3 heads (tm == wave).
__global__ __launch_bounds__(256, 4) void k_fused(const float* __restrict__ x,
                                                  const unsigned short* __restrict__ w1k,
                                                  const unsigned short* __restrict__ w1v,
                                                  const unsigned short* __restrict__ w1q,
                                                  const unsigned short* __restrict__ w2p,
                                                  const float* __restrict__ bias3,
                                                  const float* __restrict__ b2,
                                                  float* __restrict__ out)
{
    __shared__ __align__(16) unsigned short smem[13056];   // 26112 B
    unsigned short* Kr = smem;
    unsigned short* Vt = smem + 6144;
    float* o2 = reinterpret_cast<float*>(smem);            // aliases K+Vt (phase C only)

    const float* b1k = bias3;
    const float* b1v = bias3 + 96;
    const float* b1q = bias3 + 192;

    const int tid = threadIdx.x;
    const int win = blockIdx.x;
    const int b = win >> 6, wy = (win >> 3) & 7, wx = win & 7;
    const int wave = tid >> 6, lane = tid & 63;
    const int l15 = lane & 15, qd = lane >> 4;

    // ---- Phase A: QKV; K,V via x32 -> LDS; Q^T via x16 -> registers ----
    short4v bQ[6];                                         // [H*2+kt] QK^T B-frags
    {
        int pos = wave * 16 + l15;                         // rows >=49 garbage (harmless)
        int iy = pos / 7, ix = pos - iy * 7;
        int h = wy * 7 + iy + 4; if (h >= 56) h -= 56;     // undo roll(-4)
        int w = wx * 7 + ix + 4; if (w >= 56) w -= 56;
        const float* xr = x + ((size_t)b * 3136 + h * 56 + w) * 96;

        bf16x8 aX0 = ldf32(xr + qd * 8);
        bf16x8 aX1 = ldf32(xr + 32 + qd * 8);
        bf16x8 aX2 = ldf32(xr + 64 + qd * 8);
        short4v bX[6];                                     // Q^T B-frags (x row slices)
#pragma unroll
        for (int ks = 0; ks < 6; ++ks){
            f32x4 v = *reinterpret_cast<const f32x4*>(xr + ks * 16 + qd * 4);
            u32x2 p; p[0] = pk2(v[0], v[1]); p[1] = pk2(v[2], v[3]);
            bX[ks] = __builtin_bit_cast(short4v, p);
        }

        f32x4 acc[12];
#pragma unroll
        for (int n = 0; n < 6; ++n){                       // K
            const unsigned short* wf = w1k + (size_t)(n * 3) * 512 + lane * 8;
            f32x4 a = {0.f, 0.f, 0.f, 0.f};
            a = mfma_bf16(aX0, ldfrag(wf), a);
            a = mfma_bf16(aX1, ldfrag(wf + 512), a);
            a = mfma_bf16(aX2, ldfrag(wf + 1024), a);
            acc[n] = a;
        }
#pragma unroll
        for (int n = 0; n < 6; ++n){                       // V
            const unsigned short* wf = w1v + (size_t)(n * 3) * 512 + lane * 8;
            f32x4 a = {0.f, 0.f, 0.f, 0.f};
            a = mfma_bf16(aX0, ldfrag(wf), a);
            a = mfma_bf16(aX1, ldfrag(wf + 512), a);
            a = mfma_bf16(aX2, ldfrag(wf + 1024), a);
            acc[6 + n] = a;
        }

        // K -> swizzled LDS [H][pos][eh] (chunk xor), V -> Vt [H][eh][pos]
#pragma unroll
        for (int n = 0; n < 6; ++n){
            int H = n >> 1;
            int eh = ((n & 1) << 4) + l15;
            int ch = eh >> 3;
            float bb = b1k[n * 16 + l15];
#pragma unroll
            for (int r = 0; r < 4; ++r){
                int p = wave * 16 + qd * 4 + r;
                int chs = ch ^ ((p >> 1) & 3);
                Kr[H * 2048 + p * 32 + chs * 8 + (eh & 7)] = f2bf(acc[n][r] + bb);
            }
        }
#pragma unroll
        for (int n = 0; n < 6; ++n){
            int H = n >> 1;
            int eh = ((n & 1) << 4) + l15;
            float bb = b1v[n * 16 + l15];
#pragma unroll
            for (int r = 0; r < 4; ++r){
                int p = wave * 16 + qd * 4 + r;
                Vt[(H * 32 + eh) * VSTR + p] = f2bf(acc[6 + n][r] + bb);
            }
        }

        // Q^T (x16): accQ[qt][r] = s*Q[pos=w*16+l15][eh' = qt*16+qd*4+r]
#pragma unroll
        for (int qt = 0; qt < 6; ++qt){
            const unsigned short* wf = w1q + (size_t)(qt * 3) * 512 + lane * 8;
            f32x4 a = {0.f, 0.f, 0.f, 0.f};
#pragma unroll
            for (int p = 0; p < 3; ++p){
                u32x4 wv = *reinterpret_cast<const u32x4*>(wf + p * 512);
                u32x2 wl = {wv[0], wv[1]}, wh = {wv[2], wv[3]};
                a = mfma16(__builtin_bit_cast(short4v, wl), bX[2 * p],     a);
                a = mfma16(__builtin_bit_cast(short4v, wh), bX[2 * p + 1], a);
            }
            f32x4 bq = *reinterpret_cast<const f32x4*>(b1q + qt * 16 + qd * 4);
            u32x2 pq;
            pq[0] = pk2(a[0] + bq[0], a[1] + bq[1]);
            pq[1] = pk2(a[2] + bq[2], a[3] + bq[3]);
            bQ[qt] = __builtin_bit_cast(short4v, pq);
        }
    }
    __syncthreads();

    // ---- Phase B: attention; S^T = K·Q^T (x16); P stays in registers as bP frags ----
    const bool rowm = (wy == 7), colm = (wx == 7);
    const float NEGINF = -__builtin_inff();
    unsigned int m49 = 0, m28 = 0, m7 = 0;
#pragma unroll
    for (int tn = 0; tn < 4; ++tn)
#pragma unroll
        for (int r = 0; r < 4; ++r){
            int col = tn * 16 + qd * 4 + r;
            int bit = tn * 4 + r;
            m49 |= (unsigned)(col >= 49) << bit;
            m28 |= (unsigned)(col >= 28) << bit;
            m7  |= (unsigned)((col % 7) >= 4) << bit;
        }
    const int qrow = wave * 16 + l15;                      // tm == wave
    const bool rhi = (qrow >= 28);
    const bool rc7 = ((qrow % 7) >= 4);

    short4v aO[6];                                         // phase-C A-frags [H*2+et]
#pragma unroll
    for (int H = 0; H < 3; ++H){
        f32x4 S[4];
#pragma unroll
        for (int tn = 0; tn < 4; ++tn){
            f32x4 s = {0.f, 0.f, 0.f, 0.f};
#pragma unroll
            for (int kt = 0; kt < 2; ++kt){
                int p = tn * 16 + l15;
                int chs = (kt * 2 + (qd >> 1)) ^ ((p >> 1) & 3);
                const unsigned short* ka = Kr + H * 2048 + p * 32 + chs * 8 + (qd & 1) * 4;
                s = mfma16(*reinterpret_cast<const short4v*>(ka), bQ[H * 2 + kt], s);
            }
            S[tn] = s;                                     // S^T[k=tn*16+qd*4+r][q=l15]
        }

        float mx = NEGINF;
#pragma unroll
        for (int tn = 0; tn < 4; ++tn)
#pragma unroll
            for (int r = 0; r < 4; ++r){
                int bit = tn * 4 + r;
                float v = S[tn][r];                        // scale pre-folded into Q
                bool blocked = (((m49 >> bit) & 1u) != 0u)
                    || (rowm && (rhi != (((m28 >> bit) & 1u) != 0u)))
                    || (colm && (rc7 != (((m7 >> bit) & 1u) != 0u)));
                v = blocked ? NEGINF : v;
                S[tn][r] = v;
                mx = fmaxf(mx, v);
            }
        mx = fmaxf(mx, __shfl_xor(mx, 16, 64));
        mx = fmaxf(mx, __shfl_xor(mx, 32, 64));
        float sum = 0.f;
#pragma unroll
        for (int tn = 0; tn < 4; ++tn)
#pragma unroll
            for (int r = 0; r < 4; ++r){
                float e = exp2f((S[tn][r] - mx) * 1.4426950408889634f);
                S[tn][r] = e;
                sum += e;
            }
        sum += __shfl_xor(sum, 16, 64);
        sum += __shfl_xor(sum, 32, 64);
        float inv = 1.f / sum;                             // per-q (= per-lane) ✓

        short4v bP[4];                                     // PV B-frags, direct pack
#pragma unroll
        for (int tn = 0; tn < 4; ++tn){
            u32x2 pp;
            pp[0] = pk2(S[tn][0], S[tn][1]);
            pp[1] = pk2(S[tn][2], S[tn][3]);
            bP[tn] = __builtin_bit_cast(short4v, pp);
        }

        // O^T = V^T · P^T : accO[et][r] = O[q=l15][eh = et*16+qd*4+r]
#pragma unroll
        for (int et = 0; et < 2; ++et){
            f32x4 o = {0.f, 0.f, 0.f, 0.f};
#pragma unroll
            for (int kt4 = 0; kt4 < 4; ++kt4){
                const unsigned short* va = Vt + (H * 32 + et * 16 + l15) * VSTR + kt4 * 16 + qd * 4;
                o = mfma16(*reinterpret_cast<const short4v*>(va), bP[kt4], o);
            }
            u32x2 po;
            po[0] = pk2(o[0] * inv, o[1] * inv);
            po[1] = pk2(o[2] * inv, o[3] * inv);
            aO[H * 2 + et] = __builtin_bit_cast(short4v, po);
        }
    }

    // ---- Phase C: projection (x16, all operands in regs / global w2p) ----
    f32x4 acc2[6];
#pragma unroll
    for (int n = 0; n < 6; ++n){
        const unsigned short* wf = w2p + (size_t)(n * 3) * 512 + lane * 8;
        f32x4 a = {0.f, 0.f, 0.f, 0.f};
#pragma unroll
        for (int p = 0; p < 3; ++p){
            u32x4 wv = *reinterpret_cast<const u32x4*>(wf + p * 512);
            u32x2 wl = {wv[0], wv[1]}, wh = {wv[2], wv[3]};
            a = mfma16(aO[2 * p],     __builtin_bit_cast(short4v, wl), a);
            a = mfma16(aO[2 * p + 1], __builtin_bit_cast(short4v, wh), a);
        }
        acc2[n] = a;
    }
    __syncthreads();                                       // all phase-B LDS reads done

    // stage o2 (fp32 [64][100]) for coalesced 384B-row scatter
#pragma unroll
    for (int n = 0; n < 6; ++n){
        float bb = b2[n * 16 + l15];
#pragma unroll
        for (int r = 0; r < 4; ++r)
            o2[(wave * 16 + qd * 4 + r) * 100 + n * 16 + l15] = acc2[n][r] + bb;
    }
    __syncthreads();

    // scatter: contiguous fp32 rows to rolled (+3) positions
    {
        int row = tid >> 2, seg = tid & 3;
        if (row < 49){
            int iy = row / 7, ix = row - iy * 7;
            int h = wy * 7 + iy + 3; if (h >= 56) h -= 56;
            int w = wx * 7 + ix + 3; if (w >= 56) w -= 56;
            const float* src = o2 + row * 100 + seg * 24;
            float* dst = out + ((size_t)b * 3136 + h * 56 + w) * 96 + seg * 24;
#pragma unroll
            for (int v = 0; v < 6; ++v){
                f32x4 t4;
#pragma unroll
                for (int j = 0; j < 4; ++j) t4[j] = src[v * 4 + j];
                *reinterpret_cast<f32x4*>(dst + v * 4) = t4;
            }
        }
    }
}

extern "C" void kernel_launch(void* const* d_in, const int* in_sizes, int n_in,
                              void* d_out, int out_size, void* d_ws, size_t ws_size,
                              hipStream_t stream)
{
    const float* x  = (const float*)d_in[0];
    const float* w1 = (const float*)d_in[1];
    const float* b1 = (const float*)d_in[2];
    const float* w2 = (const float*)d_in[3];
    const float* b2 = (const float*)d_in[4];
    float* out = (float*)d_out;

    unsigned short* w1k = (unsigned short*)d_ws;
    unsigned short* w1v = w1k + 9216;
    unsigned short* w1q = w1k + 18432;
    unsigned short* w2p = w1k + 27648;
    float* bias3 = (float*)(w1k + 36864);

    hipLaunchKernelGGL(k_prep,  dim3(29),   dim3(256), 0, stream, w1, b1, w2, w1k, w1v, w1q, w2p, bias3);
    hipLaunchKernelGGL(k_fused, dim3(8192), dim3(256), 0, stream, x, w1k, w1v, w1q, w2p, bias3, b2, out);
}